// Round 10
// baseline (721.074 us; speedup 1.0000x reference)
//
#include <hip/hip_runtime.h>

constexpr int NN = 50000;   // nodes
constexpr int EE = 400000;  // edges
constexpr int DD = 128;     // feature dim
constexpr int HH = 4;       // heads
constexpr int LL = 3;       // layers
constexpr int QV = DD * HH; // 512
constexpr float NEG_SLOPE = 0.01f;
constexpr float LN_EPS = 1e-5f;

static inline int cdiv(int a, int b) { return (a + b - 1) / b; }

#define DEVINL __device__ __forceinline__

typedef __attribute__((ext_vector_type(8))) short bf16x8;
typedef __attribute__((ext_vector_type(8))) unsigned short u16x8;
typedef __attribute__((ext_vector_type(4))) float f32x4;

DEVINL float wave_sum(float v) {
#pragma unroll
  for (int off = 32; off; off >>= 1) v += __shfl_xor(v, off, 64);
  return v;
}

DEVINL float bf2f(unsigned short u) {
  unsigned int t = ((unsigned int)u) << 16;
  float f;
  __builtin_memcpy(&f, &t, 4);
  return f;
}
DEVINL unsigned short f2bf(float f) {
  unsigned int u;
  __builtin_memcpy(&u, &f, 4);
  u = u + 0x7fffu + ((u >> 16) & 1u);  // RNE
  return (unsigned short)(u >> 16);
}

// ---------------------------------------------------------------------------
// MFMA GEMM, BM=64: C[M,N] = A[M,K] @ B[K,N], B TRANSPOSED as Bt[N][K] bf16.
// A staged in LDS (17 KB); B fragments read DIRECTLY from global (B is tiny
// and shared by all blocks -> L1/L2-hot). BN in {64,128}.
// 256 threads = 4 waves; wave owns 16 rows x BN cols.
// EPI: 0=+bias(if non-null), 1=relu(+bias).
// ---------------------------------------------------------------------------
template <typename TA, typename TC, int EPI, int BN>
__global__ __launch_bounds__(256) void gemm64(
    const TA* __restrict__ A, const unsigned short* __restrict__ Bt,
    const float* __restrict__ bias, TC* __restrict__ C, int M, int N, int K) {
  constexpr int BM = 64, BK = 128, PAD = 4;
  constexpr int NF = BN / 16;
  __shared__ unsigned short As[BM][BK + PAD];
  const int tid = threadIdx.x;
  const int wave = tid >> 6, lane = tid & 63;
  const int l15 = lane & 15, l4 = lane >> 4;
  const int brow = blockIdx.y * BM, bcol = blockIdx.x * BN;
  const int wr = wave * 16;

  f32x4 acc[NF] = {};

  for (int k0 = 0; k0 < K; k0 += BK) {
    {
      const int row = tid >> 2, col0 = (tid & 3) * 32;
      const int gr = brow + row;
      const bool ok = (gr < M);
      if constexpr (sizeof(TA) == 2) {
        const unsigned short* srow = (const unsigned short*)A + (size_t)gr * K + k0 + col0;
#pragma unroll
        for (int j = 0; j < 4; j++) {
          u16x8 val = {};
          if (ok) val = *(const u16x8*)(srow + j * 8);
          *(u16x8*)&As[row][col0 + j * 8] = val;
        }
      } else {
        const float* srow = (const float*)A + (size_t)gr * K + k0 + col0;
#pragma unroll
        for (int j = 0; j < 4; j++) {
          u16x8 val = {};
          if (ok) {
            float4 f0 = *(const float4*)(srow + j * 8);
            float4 f1 = *(const float4*)(srow + j * 8 + 4);
            val[0] = f2bf(f0.x); val[1] = f2bf(f0.y); val[2] = f2bf(f0.z); val[3] = f2bf(f0.w);
            val[4] = f2bf(f1.x); val[5] = f2bf(f1.y); val[6] = f2bf(f1.z); val[7] = f2bf(f1.w);
          }
          *(u16x8*)&As[row][col0 + j * 8] = val;
        }
      }
    }
    __syncthreads();
#pragma unroll
    for (int kk = 0; kk < 4; kk++) {
      bf16x8 a = *(const bf16x8*)&As[wr + l15][kk * 32 + l4 * 8];
      bf16x8 b[NF];
#pragma unroll
      for (int n = 0; n < NF; n++)
        b[n] = *(const bf16x8*)(Bt + (size_t)(bcol + n * 16 + l15) * K + k0 + kk * 32 + l4 * 8);
#pragma unroll
      for (int n = 0; n < NF; n++)
        acc[n] = __builtin_amdgcn_mfma_f32_16x16x32_bf16(a, b[n], acc[n], 0, 0, 0);
    }
    __syncthreads();
  }

#pragma unroll
  for (int n = 0; n < NF; n++) {
    const int cc = bcol + n * 16 + l15;
#pragma unroll
    for (int j = 0; j < 4; j++) {
      const int rr = brow + wr + l4 * 4 + j;
      if (rr >= M) continue;
      float val = acc[n][j];
      if (bias) val += bias[cc];
      if constexpr (EPI == 1) val = fmaxf(val, 0.f);
      if constexpr (sizeof(TC) == 2)
        C[(size_t)rr * N + cc] = f2bf(val);
      else
        C[(size_t)rr * N + cc] = val;
    }
  }
}

// ---------------------------------------------------------------------------
// gemm_wvo: WvoT[j][r] = Wvo[r][j], Wvo[h*128+i][j] = sum_c Wv[i,h*128+c]*Wo[h*128+c,j]
// A = Wv_l [128][512] f32; Bt = Wot_l [128][512] bf16. Grid (1, 8). K=128 single step.
// ---------------------------------------------------------------------------
__global__ __launch_bounds__(256) void gemm_wvo(
    const float* __restrict__ Wv_l, const unsigned short* __restrict__ Wot_l,
    unsigned short* __restrict__ WvoT) {
  constexpr int BK = 128, PAD = 4;
  __shared__ unsigned short As[64][BK + PAD];
  const int tid = threadIdx.x;
  const int wave = tid >> 6, lane = tid & 63;
  const int l15 = lane & 15, l4 = lane >> 4;
  const int brow = blockIdx.y * 64;  // output row block in [0,512)
  const int hh = brow >> 7;          // head (uniform per block)
  const int wr = wave * 16;

  f32x4 acc[8] = {};
  {
    const int row = tid >> 2, col0 = (tid & 3) * 32;
    const int i = (brow + row) & 127;
    const float* srow = Wv_l + (size_t)i * QV + hh * DD + col0;
#pragma unroll
    for (int j = 0; j < 4; j++) {
      float4 f0 = *(const float4*)(srow + j * 8);
      float4 f1 = *(const float4*)(srow + j * 8 + 4);
      u16x8 val;
      val[0] = f2bf(f0.x); val[1] = f2bf(f0.y); val[2] = f2bf(f0.z); val[3] = f2bf(f0.w);
      val[4] = f2bf(f1.x); val[5] = f2bf(f1.y); val[6] = f2bf(f1.z); val[7] = f2bf(f1.w);
      *(u16x8*)&As[row][col0 + j * 8] = val;
    }
  }
  __syncthreads();
#pragma unroll
  for (int kk = 0; kk < 4; kk++) {
    bf16x8 a = *(const bf16x8*)&As[wr + l15][kk * 32 + l4 * 8];
    bf16x8 b[8];
#pragma unroll
    for (int n = 0; n < 8; n++)
      b[n] = *(const bf16x8*)(Wot_l + (size_t)(n * 16 + l15) * QV + hh * DD + kk * 32 + l4 * 8);
#pragma unroll
    for (int n = 0; n < 8; n++)
      acc[n] = __builtin_amdgcn_mfma_f32_16x16x32_bf16(a, b[n], acc[n], 0, 0, 0);
  }
  // write transposed: WvoT[cc][rr]
#pragma unroll
  for (int n = 0; n < 8; n++) {
    const int cc = n * 16 + l15;
#pragma unroll
    for (int j = 0; j < 4; j++) {
      const int rr = brow + wr + l4 * 4 + j;
      WvoT[(size_t)cc * 512 + rr] = f2bf(acc[n][j]);
    }
  }
}

// ---------------------------------------------------------------------------
// Fused: h = relu( (LN(agh @ Wvo + h)*lng+lnb) * (1+sigmoid(K*gv1+gv0)) + bl )
// BM=64, N=128, K=512. A staged in LDS; B (WvoT, 128 KB, shared) read direct
// from global. Wave owns 16 full rows -> in-wave LN. In-place h.
// ---------------------------------------------------------------------------
__global__ __launch_bounds__(256) void gemm_wo_ln(
    const unsigned short* __restrict__ Aagg, const unsigned short* __restrict__ Bt,
    const float* __restrict__ Kf, const float* __restrict__ gv,
    const float* __restrict__ lng, const float* __restrict__ lnb,
    const float* __restrict__ bl, unsigned short* __restrict__ h, int M) {
  constexpr int BM = 64, BK = 128, PAD = 4, K = 512, N = 128;
  __shared__ unsigned short As[BM][BK + PAD];
  const int tid = threadIdx.x;
  const int wave = tid >> 6, lane = tid & 63;
  const int l15 = lane & 15, l4 = lane >> 4;
  const int brow = blockIdx.y * BM;
  const int wr = wave * 16;

  f32x4 acc[8] = {};

  for (int k0 = 0; k0 < K; k0 += BK) {
    {
      const int row = tid >> 2, col0 = (tid & 3) * 32;
      const int gr = brow + row;
      const bool ok = (gr < M);
      const unsigned short* srow = Aagg + (size_t)gr * K + k0 + col0;
#pragma unroll
      for (int j = 0; j < 4; j++) {
        u16x8 val = {};
        if (ok) val = *(const u16x8*)(srow + j * 8);
        *(u16x8*)&As[row][col0 + j * 8] = val;
      }
    }
    __syncthreads();
#pragma unroll
    for (int kk = 0; kk < 4; kk++) {
      bf16x8 a = *(const bf16x8*)&As[wr + l15][kk * 32 + l4 * 8];
      bf16x8 b[8];
#pragma unroll
      for (int n = 0; n < 8; n++)
        b[n] = *(const bf16x8*)(Bt + (size_t)(n * 16 + l15) * K + k0 + kk * 32 + l4 * 8);
#pragma unroll
      for (int n = 0; n < 8; n++)
        acc[n] = __builtin_amdgcn_mfma_f32_16x16x32_bf16(a, b[n], acc[n], 0, 0, 0);
    }
    __syncthreads();
  }

#pragma unroll
  for (int j = 0; j < 4; j++) {
    const int rr = brow + wr + l4 * 4 + j;
    const bool ok = (rr < M);
    float s = 0.f, q = 0.f;
#pragma unroll
    for (int n = 0; n < 8; n++) {
      const int cc = n * 16 + l15;
      float val = acc[n][j] + (ok ? bf2f(h[(size_t)rr * N + cc]) : 0.f);
      acc[n][j] = val;
      s += val;
      q += val * val;
    }
#pragma unroll
    for (int off = 1; off < 16; off <<= 1) {
      s += __shfl_xor(s, off, 64);
      q += __shfl_xor(q, off, 64);
    }
    const float mean = s * (1.f / 128.f);
    const float var = q * (1.f / 128.f) - mean * mean;
    const float rs = rsqrtf(var + LN_EPS);
    const float kn = ok ? Kf[rr] : 0.f;
#pragma unroll
    for (int n = 0; n < 8; n++) {
      const int cc = n * 16 + l15;
      const float y = (acc[n][j] - mean) * rs * lng[cc] + lnb[cc];
      const float g = 1.f / (1.f + __expf(-(kn * gv[cc] + gv[128 + cc])));
      if (ok) h[(size_t)rr * N + cc] = f2bf(fmaxf(y * (1.f + g) + bl[cc], 0.f));
    }
  }
}

// ---------------------------------------------------------------------------
// weight transposes (f32 -> bf16, [N][K] layout): Wint, Woutt, Wot
// ---------------------------------------------------------------------------
__global__ void transp_all(const float* __restrict__ W_in, const float* __restrict__ W_out,
                           const float* __restrict__ Wo,
                           unsigned short* __restrict__ Wint, unsigned short* __restrict__ Woutt,
                           unsigned short* __restrict__ Wot) {
  int idx = blockIdx.x * 256 + threadIdx.x;
  if (idx < 16384) {  // Wint [128][128] <- W_in [128][128]
    int n = idx >> 7, k = idx & 127;
    Wint[idx] = f2bf(W_in[k * 128 + n]);
    return;
  }
  idx -= 16384;
  if (idx < 8192) {  // Woutt [64][128] <- W_out [128][64]
    int n = idx >> 7, k = idx & 127;
    Woutt[idx] = f2bf(W_out[k * 64 + n]);
    return;
  }
  idx -= 8192;
  if (idx < 3 * 65536) {  // Wot [3][128][512] <- Wo [3][512][128]
    int l = idx >> 16, r = idx & 65535;
    int n = r >> 9, k = r & 511;
    Wot[idx] = f2bf(Wo[l * 65536 + k * 128 + n]);
  }
}

// ---------------------------------------------------------------------------
// CSR build (multi-block scan)
// ---------------------------------------------------------------------------
__global__ void zero_int(int* __restrict__ p, int n) {
  int i = blockIdx.x * blockDim.x + threadIdx.x;
  if (i < n) p[i] = 0;
}

__global__ void histo_kernel(const int* __restrict__ dst, int* __restrict__ deg, int E) {
  int e = blockIdx.x * blockDim.x + threadIdx.x;
  if (e < E) atomicAdd(&deg[dst[e]], 1);
}

__global__ __launch_bounds__(1024) void scan_blocks(
    const int* __restrict__ deg, int* __restrict__ rowptr, int* __restrict__ blocksum, int N) {
  __shared__ int lds[1024];
  const int tid = threadIdx.x;
  const int i = blockIdx.x * 1024 + tid;
  int x = (i < N) ? deg[i] : 0;
  lds[tid] = x;
  __syncthreads();
  for (int off = 1; off < 1024; off <<= 1) {
    int t = (tid >= off) ? lds[tid - off] : 0;
    __syncthreads();
    lds[tid] += t;
    __syncthreads();
  }
  if (i < N) rowptr[i] = lds[tid] - x;
  if (tid == 1023) blocksum[blockIdx.x] = lds[1023];
}

__global__ void scan_sums(int* __restrict__ blocksum, int* __restrict__ rowptr, int NB, int N) {
  if (threadIdx.x == 0 && blockIdx.x == 0) {
    int run = 0;
    for (int b = 0; b < NB; b++) {
      int t = blocksum[b];
      blocksum[b] = run;
      run += t;
    }
    rowptr[N] = run;
  }
}

__global__ void scan_apply(int* __restrict__ rowptr, int* __restrict__ cursor,
                           const int* __restrict__ blocksum, int N) {
  int i = blockIdx.x * blockDim.x + threadIdx.x;
  if (i < N) {
    int val = rowptr[i] + blocksum[i >> 10];
    rowptr[i] = val;
    cursor[i] = val;
  }
}

__global__ void scatter_kernel(const int* __restrict__ src, const int* __restrict__ dst,
                               int* __restrict__ cursor, int* __restrict__ esrc,
                               int* __restrict__ edst, int E) {
  int e = blockIdx.x * blockDim.x + threadIdx.x;
  if (e < E) {
    int d = dst[e];
    int pos = atomicAdd(&cursor[d], 1);
    esrc[pos] = src[e];
    edst[pos] = d;
  }
}

// ---------------------------------------------------------------------------
// layer_pre: one wave per output dot-product (1288 waves = 322 blocks).
// ---------------------------------------------------------------------------
__global__ __launch_bounds__(256) void layer_pre(
    const float* __restrict__ wq, const float* __restrict__ wv,
    const float* __restrict__ att_l, const float* __restrict__ wkw,
    const float* __restrict__ wkb, const float* __restrict__ gw,
    const float* __restrict__ gb,
    float* __restrict__ wqv_a, float* __restrict__ kk, float* __restrict__ gv) {
  const int wid = blockIdx.x * 4 + (threadIdx.x >> 6);
  const int lane = threadIdx.x & 63;
  if (wid < 1024) {
    int k = wid >> 3, o = wid & 7;
    const float* w;
    const float* a;
    if (o < 4) {
      w = wq + (size_t)k * QV + o * DD;
      a = att_l + o * 3 * DD + DD;  // a_q
    } else {
      w = wv + (size_t)k * QV + (o - 4) * DD;
      a = att_l + (o - 4) * 3 * DD + 2 * DD;  // a_v
    }
    float s = wave_sum(w[lane] * a[lane] + w[lane + 64] * a[lane + 64]);
    if (lane == 0) wqv_a[wid] = s;
  } else if (wid < 1152) {
    int c = wid - 1024;
    float s = wave_sum(wkw[lane] * gw[(size_t)lane * DD + c] +
                       wkw[lane + 64] * gw[(size_t)(lane + 64) * DD + c]);
    if (lane == 0) gv[c] = s;
  } else if (wid < 1280) {
    int c = wid - 1152;
    float s = wave_sum(wkb[lane] * gw[(size_t)lane * DD + c] +
                       wkb[lane + 64] * gw[(size_t)(lane + 64) * DD + c]);
    if (lane == 0) gv[DD + c] = s + gb[c];
  } else if (wid < 1288) {
    int t = wid - 1280;
    const float* a = att_l + (t & 3) * 3 * DD;  // a_k
    const float* w = (t < 4) ? wkw : wkb;
    float s = wave_sum(w[lane] * a[lane] + w[lane + 64] * a[lane + 64]);
    if (lane == 0) kk[t] = s;
  }
}

// ---------------------------------------------------------------------------
// node_pre2: skq[n,h] = K[n]*kk1[h]+kk0[h] + h[n,:]·wqv_a[:,h]
//            svb[n,h] = h[n,:]·wqv_a[:,4+h].  One wave per node. h is bf16.
// ---------------------------------------------------------------------------
__global__ __launch_bounds__(256) void node_pre2(
    const unsigned short* __restrict__ h, const float* __restrict__ Kf,
    const float* __restrict__ wqv_a, const float* __restrict__ kk,
    float* __restrict__ skq, float* __restrict__ svb, int N) {
  __shared__ float W[DD][8];
  __shared__ float kkl[8];
  const int tid = threadIdx.x;
  for (int i = tid; i < DD * 8; i += 256) W[i >> 3][i & 7] = wqv_a[i];
  if (tid < 8) kkl[tid] = kk[tid];
  __syncthreads();
  const int wid = tid >> 6, lane = tid & 63;
  const int n = blockIdx.x * 4 + wid;
  if (n >= N) return;
  const float h0 = bf2f(h[(size_t)n * DD + lane]);
  const float h1 = bf2f(h[(size_t)n * DD + lane + 64]);
  float r[8];
#pragma unroll
  for (int o = 0; o < 8; o++) r[o] = wave_sum(h0 * W[lane][o] + h1 * W[lane + 64][o]);
  if (lane == 0) {
    const float kn = Kf[n];
    *reinterpret_cast<float4*>(skq + (size_t)n * 4) =
        make_float4(r[0] + kn * kkl[0] + kkl[4], r[1] + kn * kkl[1] + kkl[5],
                    r[2] + kn * kkl[2] + kkl[6], r[3] + kn * kkl[3] + kkl[7]);
    *reinterpret_cast<float4*>(svb + (size_t)n * 4) = make_float4(r[4], r[5], r[6], r[7]);
  }
}

// ---------------------------------------------------------------------------
// edge_ex: per-edge softmax weights, AoS float4 per edge (all 4 heads).
// ---------------------------------------------------------------------------
__global__ __launch_bounds__(256) void edge_ex(
    const int* __restrict__ esrc, const int* __restrict__ edst,
    const float* __restrict__ skq, const float* __restrict__ svb,
    float4* __restrict__ ext4, int E) {
  const int e = blockIdx.x * 256 + threadIdx.x;
  if (e >= E) return;
  const int s = esrc[e], d = edst[e];
  const float4 sv = *(const float4*)(svb + (size_t)s * 4);
  const float4 kq = *(const float4*)(skq + (size_t)d * 4);
  float sc[4] = {kq.x + sv.x, kq.y + sv.y, kq.z + sv.z, kq.w + sv.w};
  float ex[4];
#pragma unroll
  for (int hh = 0; hh < 4; hh++) {
    float vv = sc[hh] > 0.f ? sc[hh] : NEG_SLOPE * sc[hh];
    ex[hh] = __expf(fminf(vv, 60.f));
  }
  ext4[e] = make_float4(ex[0], ex[1], ex[2], ex[3]);
}

// ---------------------------------------------------------------------------
// attn_gather: agh[n][h*128+c] = (Σ_e ex^h_e · h[src_e][c]) / Σ_e ex^h_e.
// One wave per node; lane owns cols {lane*2, lane*2+1} of h (4B gather/lane).
// h table is 12.8 MB (L2/L3-resident). Unroll x8.
// ---------------------------------------------------------------------------
__global__ __launch_bounds__(256) void attn_gather(
    const int* __restrict__ rowptr, const int* __restrict__ esrc,
    const float4* __restrict__ ext4, const unsigned short* __restrict__ h,
    unsigned short* __restrict__ agh, int N) {
  const int wid = threadIdx.x >> 6;
  const int lane = threadIdx.x & 63;
  const int n = blockIdx.x * 4 + wid;
  if (n >= N) return;
  const int beg = rowptr[n];
  const int end = rowptr[n + 1];
  const int c0 = lane * 2;

  float a0[4] = {}, a1[4] = {};
  float sumw[4] = {};

  for (int base = beg; base < end; base += 64) {
    const int cnt = min(64, end - base);
    int myidx = 0;
    if (lane < cnt) myidx = esrc[base + lane];
    int j = 0;
    for (; j + 8 <= cnt; j += 8) {
      int s[8];
      unsigned int wv[8];
      float4 ee[8];
#pragma unroll
      for (int u = 0; u < 8; u++) s[u] = __shfl(myidx, j + u, 64);
#pragma unroll
      for (int u = 0; u < 8; u++) wv[u] = *(const unsigned int*)(h + (size_t)s[u] * DD + c0);
#pragma unroll
      for (int u = 0; u < 8; u++) ee[u] = ext4[base + j + u];
#pragma unroll
      for (int u = 0; u < 8; u++) {
        const float lo = bf2f((unsigned short)(wv[u] & 0xffffu));
        const float hi = bf2f((unsigned short)(wv[u] >> 16));
        a0[0] += ee[u].x * lo; a1[0] += ee[u].x * hi;
        a0[1] += ee[u].y * lo; a1[1] += ee[u].y * hi;
        a0[2] += ee[u].z * lo; a1[2] += ee[u].z * hi;
        a0[3] += ee[u].w * lo; a1[3] += ee[u].w * hi;
        sumw[0] += ee[u].x; sumw[1] += ee[u].y;
        sumw[2] += ee[u].z; sumw[3] += ee[u].w;
      }
    }
    for (; j < cnt; j++) {
      const int s0 = __shfl(myidx, j, 64);
      const unsigned int w0 = *(const unsigned int*)(h + (size_t)s0 * DD + c0);
      const float4 ee = ext4[base + j];
      const float lo = bf2f((unsigned short)(w0 & 0xffffu));
      const float hi = bf2f((unsigned short)(w0 >> 16));
      a0[0] += ee.x * lo; a1[0] += ee.x * hi;
      a0[1] += ee.y * lo; a1[1] += ee.y * hi;
      a0[2] += ee.z * lo; a1[2] += ee.z * hi;
      a0[3] += ee.w * lo; a1[3] += ee.w * hi;
      sumw[0] += ee.x; sumw[1] += ee.y; sumw[2] += ee.z; sumw[3] += ee.w;
    }
  }
  const bool has = (end > beg);
#pragma unroll
  for (int hh = 0; hh < 4; hh++) {
    const float inv = has ? 1.f / sumw[hh] : 0.f;
    const unsigned int packed =
        (unsigned int)f2bf(a0[hh] * inv) | ((unsigned int)f2bf(a1[hh] * inv) << 16);
    *(unsigned int*)(agh + (size_t)n * QV + hh * DD + c0) = packed;
  }
}

// ---------------------------------------------------------------------------
extern "C" void kernel_launch(void* const* d_in, const int* in_sizes, int n_in,
                              void* d_out, int out_size, void* d_ws, size_t ws_size,
                              hipStream_t stream) {
  const float* x = (const float*)d_in[0];
  const int* edge = (const int*)d_in[1];
  const float* Kf = (const float*)d_in[2];
  const float* W_in = (const float*)d_in[3];
  const float* b_in = (const float*)d_in[4];
  const float* Wk_w = (const float*)d_in[5];
  const float* Wk_b = (const float*)d_in[6];
  const float* Wq = (const float*)d_in[7];
  const float* Wv = (const float*)d_in[8];
  const float* att = (const float*)d_in[9];
  const float* Wo = (const float*)d_in[10];
  const float* b_l = (const float*)d_in[11];
  const float* ln_g = (const float*)d_in[12];
  const float* ln_b = (const float*)d_in[13];
  const float* gate_w = (const float*)d_in[14];
  const float* gate_b = (const float*)d_in[15];
  const float* W_out = (const float*)d_in[16];
  const float* b_out = (const float*)d_in[17];
  float* out = (float*)d_out;

  const int* src = edge;
  const int* dst = edge + EE;

  // ---- workspace carve-up ----
  char* w = (char*)d_ws;
  auto alloc = [&](size_t bytes) {
    char* p = w;
    w += (bytes + 255) & ~(size_t)255;
    return p;
  };
  unsigned short* h = (unsigned short*)alloc((size_t)NN * DD * 2);     // 12.8 MB
  unsigned short* agh = (unsigned short*)alloc((size_t)NN * QV * 2);   // 51.2 MB
  float* skq = (float*)alloc((size_t)NN * HH * 4);
  float* svb = (float*)alloc((size_t)NN * HH * 4);
  float* wqv_a = (float*)alloc(DD * 8 * 4);
  float* kk = (float*)alloc(8 * 4);
  float* gv = (float*)alloc(2 * DD * 4);
  int* deg = (int*)alloc((size_t)NN * 4);
  int* rowptr = (int*)alloc((size_t)(NN + 1) * 4);
  int* cursor = (int*)alloc((size_t)NN * 4);
  int* esrc = (int*)alloc((size_t)EE * 4);
  int* edst = (int*)alloc((size_t)EE * 4);
  float4* ext4 = (float4*)alloc((size_t)EE * 16);
  int* blocksum = (int*)alloc((size_t)64 * 4);
  unsigned short* Wint = (unsigned short*)alloc((size_t)DD * DD * 2);
  unsigned short* Woutt = (unsigned short*)alloc((size_t)64 * DD * 2);
  unsigned short* Wot = (unsigned short*)alloc((size_t)LL * DD * QV * 2);  // [3][128][512]
  unsigned short* WvoT = (unsigned short*)alloc((size_t)DD * QV * 2);      // [128][512]

  dim3 blk(256);
  const int NB = cdiv(NN, 1024);
  const int GY = cdiv(NN, 64);  // 782

  // ---- CSR build ----
  zero_int<<<cdiv(NN, 256), blk, 0, stream>>>(deg, NN);
  histo_kernel<<<cdiv(EE, 256), blk, 0, stream>>>(dst, deg, EE);
  scan_blocks<<<NB, 1024, 0, stream>>>(deg, rowptr, blocksum, NN);
  scan_sums<<<1, 64, 0, stream>>>(blocksum, rowptr, NB, NN);
  scan_apply<<<cdiv(NN, 256), blk, 0, stream>>>(rowptr, cursor, blocksum, NN);
  scatter_kernel<<<cdiv(EE, 256), blk, 0, stream>>>(src, dst, cursor, esrc, edst, EE);

  // ---- weight transposes ----
  transp_all<<<cdiv(16384 + 8192 + 3 * 65536, 256), blk, 0, stream>>>(
      W_in, W_out, Wo, Wint, Woutt, Wot);

  // ---- h = relu(x @ W_in + b_in)  (bf16 out) ----
  gemm64<float, unsigned short, 1, 128><<<dim3(1, GY), blk, 0, stream>>>(
      x, Wint, b_in, h, NN, DD, DD);

  for (int l = 0; l < LL; l++) {
    const float* wkw = Wk_w + (size_t)l * DD;
    const float* wkb = Wk_b + (size_t)l * DD;
    const float* wq = Wq + (size_t)l * DD * QV;
    const float* wv = Wv + (size_t)l * DD * QV;
    const float* att_l = att + (size_t)l * HH * 3 * DD;
    const float* bl = b_l + (size_t)l * DD;
    const float* lng = ln_g + (size_t)l * DD;
    const float* lnb = ln_b + (size_t)l * DD;
    const float* gw = gate_w + (size_t)l * DD * DD;
    const float* gb = gate_b + (size_t)l * DD;

    layer_pre<<<cdiv(1288, 4), blk, 0, stream>>>(wq, wv, att_l, wkw, wkb, gw, gb, wqv_a, kk, gv);

    // WvoT = (blockdiag(Wv_h) @ Wo)^T  (tiny)
    gemm_wvo<<<dim3(1, 8), blk, 0, stream>>>(wv, Wot + (size_t)l * DD * QV, WvoT);

    // per-node score components
    node_pre2<<<cdiv(NN, 4), blk, 0, stream>>>(h, Kf, wqv_a, kk, skq, svb, NN);

    // per-edge softmax weights (AoS float4)
    edge_ex<<<cdiv(EE, 256), blk, 0, stream>>>(esrc, edst, skq, svb, ext4, EE);

    // gather h-rows weighted per head -> agh
    attn_gather<<<cdiv(NN, 4), blk, 0, stream>>>(rowptr, esrc, ext4, h, agh, NN);

    // h = relu(LN(agh @ Wvo + h)*lng+lnb * gate + bl)  -- fused, in place
    gemm_wo_ln<<<dim3(1, GY), blk, 0, stream>>>(
        agh, WvoT, Kf, gv, lng, lnb, bl, h, NN);
  }

  // ---- out = h @ W_out + b_out  (f32) ----
  gemm64<unsigned short, float, 0, 64><<<dim3(1, GY), blk, 0, stream>>>(
      h, Woutt, b_out, out, NN, 64, DD);
}

// Round 11
// 540.815 us; speedup vs baseline: 1.3333x; 1.3333x over previous
//
#include <hip/hip_runtime.h>

constexpr int NN = 50000;   // nodes
constexpr int EE = 400000;  // edges
constexpr int DD = 128;     // feature dim
constexpr int HH = 4;       // heads
constexpr int LL = 3;       // layers
constexpr int QV = DD * HH; // 512
constexpr float NEG_SLOPE = 0.01f;
constexpr float LN_EPS = 1e-5f;

static inline int cdiv(int a, int b) { return (a + b - 1) / b; }

#define DEVINL __device__ __forceinline__

typedef __attribute__((ext_vector_type(8))) short bf16x8;
typedef __attribute__((ext_vector_type(8))) unsigned short u16x8;
typedef __attribute__((ext_vector_type(4))) float f32x4;

DEVINL float wave_sum(float v) {
#pragma unroll
  for (int off = 32; off; off >>= 1) v += __shfl_xor(v, off, 64);
  return v;
}

DEVINL float bf2f(unsigned short u) {
  unsigned int t = ((unsigned int)u) << 16;
  float f;
  __builtin_memcpy(&f, &t, 4);
  return f;
}
DEVINL unsigned short f2bf(float f) {
  unsigned int u;
  __builtin_memcpy(&u, &f, 4);
  u = u + 0x7fffu + ((u >> 16) & 1u);  // RNE
  return (unsigned short)(u >> 16);
}

DEVINL u16x8 pack2f4(float4 f0, float4 f1) {
  u16x8 val;
  val[0] = f2bf(f0.x); val[1] = f2bf(f0.y); val[2] = f2bf(f0.z); val[3] = f2bf(f0.w);
  val[4] = f2bf(f1.x); val[5] = f2bf(f1.y); val[6] = f2bf(f1.z); val[7] = f2bf(f1.w);
  return val;
}

// ---------------------------------------------------------------------------
// MFMA GEMM, BM=64, BK=64: C[M,N] = A[M,K] @ B[K,N], B TRANSPOSED Bt[N][K] bf16.
// LDS ~25.5 KB (A+B tiles, PAD=4 -> 2-bank row step, conflict-light).
// Reg-staged pipeline: next tile's global loads issued before MFMA cluster.
// BN in {64,128}. 256 threads = 4 waves; wave owns 16 rows x BN cols.
// EPI: 0=+bias(if non-null), 1=relu(+bias).
// ---------------------------------------------------------------------------
template <typename TA, typename TC, int EPI, int BN>
__global__ __launch_bounds__(256) void gemm64(
    const TA* __restrict__ A, const unsigned short* __restrict__ Bt,
    const float* __restrict__ bias, TC* __restrict__ C, int M, int N, int K) {
  constexpr int BM = 64, BK = 64, PAD = 4;
  constexpr int NF = BN / 16;
  __shared__ unsigned short As[BM][BK + PAD];
  __shared__ unsigned short Bs[BN][BK + PAD];
  const int tid = threadIdx.x;
  const int wave = tid >> 6, lane = tid & 63;
  const int l15 = lane & 15, l4 = lane >> 4;
  const int brow = blockIdx.y * BM, bcol = blockIdx.x * BN;
  const int wr = wave * 16;

  // staging coords: A 16 shorts/thread, B (BN*64/256) shorts/thread
  const int arow = tid >> 2, acol = (tid & 3) * 16;
  const int gr = brow + arow;
  const bool aok = (gr < M);
  constexpr int BRS = (BN == 128) ? 1 : 2;  // B rows per thread-group shift
  const int brw = (BN == 128) ? (tid >> 1) : (tid >> 2);
  const int bcl = (BN == 128) ? (tid & 1) * 32 : (tid & 3) * 16;
  constexpr int BNV = (BN == 128) ? 4 : 2;  // u16x8 per thread for B

  u16x8 ra[2], rb[4];

  auto loadA = [&](int k0) {
    if constexpr (sizeof(TA) == 2) {
      const unsigned short* p = (const unsigned short*)A + (size_t)gr * K + k0 + acol;
      ra[0] = aok ? *(const u16x8*)p : u16x8{};
      ra[1] = aok ? *(const u16x8*)(p + 8) : u16x8{};
    } else {
      const float* p = (const float*)A + (size_t)gr * K + k0 + acol;
      if (aok) {
        ra[0] = pack2f4(*(const float4*)p, *(const float4*)(p + 4));
        ra[1] = pack2f4(*(const float4*)(p + 8), *(const float4*)(p + 12));
      } else {
        ra[0] = u16x8{};
        ra[1] = u16x8{};
      }
    }
  };
  auto loadB = [&](int k0) {
    const unsigned short* p = Bt + (size_t)(bcol + brw) * K + k0 + bcl;
#pragma unroll
    for (int j = 0; j < BNV; j++) rb[j] = *(const u16x8*)(p + j * 8);
  };

  f32x4 acc[NF] = {};
  loadA(0);
  loadB(0);

  for (int k0 = 0; k0 < K; k0 += BK) {
    *(u16x8*)&As[arow][acol] = ra[0];
    *(u16x8*)&As[arow][acol + 8] = ra[1];
#pragma unroll
    for (int j = 0; j < BNV; j++) *(u16x8*)&Bs[brw][bcl + j * 8] = rb[j];
    __syncthreads();
    if (k0 + BK < K) {
      loadA(k0 + BK);
      loadB(k0 + BK);
    }
#pragma unroll
    for (int kk = 0; kk < 2; kk++) {
      bf16x8 a = *(const bf16x8*)&As[wr + l15][kk * 32 + l4 * 8];
      bf16x8 b[NF];
#pragma unroll
      for (int n = 0; n < NF; n++) b[n] = *(const bf16x8*)&Bs[n * 16 + l15][kk * 32 + l4 * 8];
#pragma unroll
      for (int n = 0; n < NF; n++)
        acc[n] = __builtin_amdgcn_mfma_f32_16x16x32_bf16(a, b[n], acc[n], 0, 0, 0);
    }
    __syncthreads();
  }

#pragma unroll
  for (int n = 0; n < NF; n++) {
    const int cc = bcol + n * 16 + l15;
#pragma unroll
    for (int j = 0; j < 4; j++) {
      const int rr = brow + wr + l4 * 4 + j;
      if (rr >= M) continue;
      float val = acc[n][j];
      if (bias) val += bias[cc];
      if constexpr (EPI == 1) val = fmaxf(val, 0.f);
      if constexpr (sizeof(TC) == 2)
        C[(size_t)rr * N + cc] = f2bf(val);
      else
        C[(size_t)rr * N + cc] = val;
    }
  }
}

// ---------------------------------------------------------------------------
// gemm_wvo: WvoT[j][r] = Wvo[r][j], Wvo[h*128+i][j] = sum_c Wv[i,h*128+c]*Wo[h*128+c,j]
// A = Wv_l [128][512] f32; Bt = Wot_l [128][512] bf16. Grid (1, 8). Tiny, one-shot.
// ---------------------------------------------------------------------------
__global__ __launch_bounds__(256) void gemm_wvo(
    const float* __restrict__ Wv_l, const unsigned short* __restrict__ Wot_l,
    unsigned short* __restrict__ WvoT) {
  constexpr int BK = 128, PAD = 4;
  __shared__ unsigned short As[64][BK + PAD];
  const int tid = threadIdx.x;
  const int wave = tid >> 6, lane = tid & 63;
  const int l15 = lane & 15, l4 = lane >> 4;
  const int brow = blockIdx.y * 64;  // output row block in [0,512)
  const int hh = brow >> 7;          // head (uniform per block)
  const int wr = wave * 16;

  f32x4 acc[8] = {};
  {
    const int row = tid >> 2, col0 = (tid & 3) * 32;
    const int i = (brow + row) & 127;
    const float* srow = Wv_l + (size_t)i * QV + hh * DD + col0;
#pragma unroll
    for (int j = 0; j < 4; j++) {
      *(u16x8*)&As[row][col0 + j * 8] =
          pack2f4(*(const float4*)(srow + j * 8), *(const float4*)(srow + j * 8 + 4));
    }
  }
  __syncthreads();
#pragma unroll
  for (int kk = 0; kk < 4; kk++) {
    bf16x8 a = *(const bf16x8*)&As[wr + l15][kk * 32 + l4 * 8];
    bf16x8 b[8];
#pragma unroll
    for (int n = 0; n < 8; n++)
      b[n] = *(const bf16x8*)(Wot_l + (size_t)(n * 16 + l15) * QV + hh * DD + kk * 32 + l4 * 8);
#pragma unroll
    for (int n = 0; n < 8; n++)
      acc[n] = __builtin_amdgcn_mfma_f32_16x16x32_bf16(a, b[n], acc[n], 0, 0, 0);
  }
  // write transposed: WvoT[cc][rr]
#pragma unroll
  for (int n = 0; n < 8; n++) {
    const int cc = n * 16 + l15;
#pragma unroll
    for (int j = 0; j < 4; j++) {
      const int rr = brow + wr + l4 * 4 + j;
      WvoT[(size_t)cc * 512 + rr] = f2bf(acc[n][j]);
    }
  }
}

// ---------------------------------------------------------------------------
// Fused: h = relu( (LN(agh @ Wvo + h)*lng+lnb) * (1+sigmoid(K*gv1+gv0)) + bl )
// BM=64, BK=64, N=128, K=512. LDS-staged A+B, reg pipeline. Wave owns 16 full
// rows -> in-wave LN. In-place h.
// ---------------------------------------------------------------------------
__global__ __launch_bounds__(256) void gemm_wo_ln(
    const unsigned short* __restrict__ Aagg, const unsigned short* __restrict__ Bt,
    const float* __restrict__ Kf, const float* __restrict__ gv,
    const float* __restrict__ lng, const float* __restrict__ lnb,
    const float* __restrict__ bl, unsigned short* __restrict__ h, int M) {
  constexpr int BM = 64, BK = 64, PAD = 4, K = 512, N = 128;
  __shared__ unsigned short As[BM][BK + PAD];
  __shared__ unsigned short Bs[N][BK + PAD];
  const int tid = threadIdx.x;
  const int wave = tid >> 6, lane = tid & 63;
  const int l15 = lane & 15, l4 = lane >> 4;
  const int brow = blockIdx.y * BM;
  const int wr = wave * 16;

  const int arow = tid >> 2, acol = (tid & 3) * 16;
  const int gr = brow + arow;
  const bool aok = (gr < M);
  const int brw = tid >> 1, bcl = (tid & 1) * 32;

  u16x8 ra[2], rb[4];
  auto loadA = [&](int k0) {
    const unsigned short* p = Aagg + (size_t)gr * K + k0 + acol;
    ra[0] = aok ? *(const u16x8*)p : u16x8{};
    ra[1] = aok ? *(const u16x8*)(p + 8) : u16x8{};
  };
  auto loadB = [&](int k0) {
    const unsigned short* p = Bt + (size_t)brw * K + k0 + bcl;
#pragma unroll
    for (int j = 0; j < 4; j++) rb[j] = *(const u16x8*)(p + j * 8);
  };

  f32x4 acc[8] = {};
  loadA(0);
  loadB(0);

  for (int k0 = 0; k0 < K; k0 += BK) {
    *(u16x8*)&As[arow][acol] = ra[0];
    *(u16x8*)&As[arow][acol + 8] = ra[1];
#pragma unroll
    for (int j = 0; j < 4; j++) *(u16x8*)&Bs[brw][bcl + j * 8] = rb[j];
    __syncthreads();
    if (k0 + BK < K) {
      loadA(k0 + BK);
      loadB(k0 + BK);
    }
#pragma unroll
    for (int kk = 0; kk < 2; kk++) {
      bf16x8 a = *(const bf16x8*)&As[wr + l15][kk * 32 + l4 * 8];
      bf16x8 b[8];
#pragma unroll
      for (int n = 0; n < 8; n++) b[n] = *(const bf16x8*)&Bs[n * 16 + l15][kk * 32 + l4 * 8];
#pragma unroll
      for (int n = 0; n < 8; n++)
        acc[n] = __builtin_amdgcn_mfma_f32_16x16x32_bf16(a, b[n], acc[n], 0, 0, 0);
    }
    __syncthreads();
  }

  // residual + in-wave LN + gate + relu, write h in place
#pragma unroll
  for (int j = 0; j < 4; j++) {
    const int rr = brow + wr + l4 * 4 + j;
    const bool ok = (rr < M);
    float s = 0.f, q = 0.f;
#pragma unroll
    for (int n = 0; n < 8; n++) {
      const int cc = n * 16 + l15;
      float val = acc[n][j] + (ok ? bf2f(h[(size_t)rr * N + cc]) : 0.f);
      acc[n][j] = val;
      s += val;
      q += val * val;
    }
#pragma unroll
    for (int off = 1; off < 16; off <<= 1) {
      s += __shfl_xor(s, off, 64);
      q += __shfl_xor(q, off, 64);
    }
    const float mean = s * (1.f / 128.f);
    const float var = q * (1.f / 128.f) - mean * mean;
    const float rs = rsqrtf(var + LN_EPS);
    const float kn = ok ? Kf[rr] : 0.f;
#pragma unroll
    for (int n = 0; n < 8; n++) {
      const int cc = n * 16 + l15;
      const float y = (acc[n][j] - mean) * rs * lng[cc] + lnb[cc];
      const float g = 1.f / (1.f + __expf(-(kn * gv[cc] + gv[128 + cc])));
      if (ok) h[(size_t)rr * N + cc] = f2bf(fmaxf(y * (1.f + g) + bl[cc], 0.f));
    }
  }
}

// ---------------------------------------------------------------------------
// weight transposes (f32 -> bf16, [N][K] layout): Wint, Woutt, Wot
// ---------------------------------------------------------------------------
__global__ void transp_all(const float* __restrict__ W_in, const float* __restrict__ W_out,
                           const float* __restrict__ Wo,
                           unsigned short* __restrict__ Wint, unsigned short* __restrict__ Woutt,
                           unsigned short* __restrict__ Wot) {
  int idx = blockIdx.x * 256 + threadIdx.x;
  if (idx < 16384) {  // Wint [128][128] <- W_in [128][128]
    int n = idx >> 7, k = idx & 127;
    Wint[idx] = f2bf(W_in[k * 128 + n]);
    return;
  }
  idx -= 16384;
  if (idx < 8192) {  // Woutt [64][128] <- W_out [128][64]
    int n = idx >> 7, k = idx & 127;
    Woutt[idx] = f2bf(W_out[k * 64 + n]);
    return;
  }
  idx -= 8192;
  if (idx < 3 * 65536) {  // Wot [3][128][512] <- Wo [3][512][128]
    int l = idx >> 16, r = idx & 65535;
    int n = r >> 9, k = r & 511;
    Wot[idx] = f2bf(Wo[l * 65536 + k * 128 + n]);
  }
}

// ---------------------------------------------------------------------------
// CSR build (multi-block scan)
// ---------------------------------------------------------------------------
__global__ void zero_int(int* __restrict__ p, int n) {
  int i = blockIdx.x * blockDim.x + threadIdx.x;
  if (i < n) p[i] = 0;
}

__global__ void histo_kernel(const int* __restrict__ dst, int* __restrict__ deg, int E) {
  int e = blockIdx.x * blockDim.x + threadIdx.x;
  if (e < E) atomicAdd(&deg[dst[e]], 1);
}

__global__ __launch_bounds__(1024) void scan_blocks(
    const int* __restrict__ deg, int* __restrict__ rowptr, int* __restrict__ blocksum, int N) {
  __shared__ int lds[1024];
  const int tid = threadIdx.x;
  const int i = blockIdx.x * 1024 + tid;
  int x = (i < N) ? deg[i] : 0;
  lds[tid] = x;
  __syncthreads();
  for (int off = 1; off < 1024; off <<= 1) {
    int t = (tid >= off) ? lds[tid - off] : 0;
    __syncthreads();
    lds[tid] += t;
    __syncthreads();
  }
  if (i < N) rowptr[i] = lds[tid] - x;
  if (tid == 1023) blocksum[blockIdx.x] = lds[1023];
}

__global__ void scan_sums(int* __restrict__ blocksum, int* __restrict__ rowptr, int NB, int N) {
  if (threadIdx.x == 0 && blockIdx.x == 0) {
    int run = 0;
    for (int b = 0; b < NB; b++) {
      int t = blocksum[b];
      blocksum[b] = run;
      run += t;
    }
    rowptr[N] = run;
  }
}

__global__ void scan_apply(int* __restrict__ rowptr, int* __restrict__ cursor,
                           const int* __restrict__ blocksum, int N) {
  int i = blockIdx.x * blockDim.x + threadIdx.x;
  if (i < N) {
    int val = rowptr[i] + blocksum[i >> 10];
    rowptr[i] = val;
    cursor[i] = val;
  }
}

__global__ void scatter_kernel(const int* __restrict__ src, const int* __restrict__ dst,
                               int* __restrict__ cursor, int* __restrict__ esrc,
                               int* __restrict__ edst, int E) {
  int e = blockIdx.x * blockDim.x + threadIdx.x;
  if (e < E) {
    int d = dst[e];
    int pos = atomicAdd(&cursor[d], 1);
    esrc[pos] = src[e];
    edst[pos] = d;
  }
}

// ---------------------------------------------------------------------------
// layer_pre: one wave per output dot-product (1288 waves = 322 blocks).
// ---------------------------------------------------------------------------
__global__ __launch_bounds__(256) void layer_pre(
    const float* __restrict__ wq, const float* __restrict__ wv,
    const float* __restrict__ att_l, const float* __restrict__ wkw,
    const float* __restrict__ wkb, const float* __restrict__ gw,
    const float* __restrict__ gb,
    float* __restrict__ wqv_a, float* __restrict__ kk, float* __restrict__ gv) {
  const int wid = blockIdx.x * 4 + (threadIdx.x >> 6);
  const int lane = threadIdx.x & 63;
  if (wid < 1024) {
    int k = wid >> 3, o = wid & 7;
    const float* w;
    const float* a;
    if (o < 4) {
      w = wq + (size_t)k * QV + o * DD;
      a = att_l + o * 3 * DD + DD;  // a_q
    } else {
      w = wv + (size_t)k * QV + (o - 4) * DD;
      a = att_l + (o - 4) * 3 * DD + 2 * DD;  // a_v
    }
    float s = wave_sum(w[lane] * a[lane] + w[lane + 64] * a[lane + 64]);
    if (lane == 0) wqv_a[wid] = s;
  } else if (wid < 1152) {
    int c = wid - 1024;
    float s = wave_sum(wkw[lane] * gw[(size_t)lane * DD + c] +
                       wkw[lane + 64] * gw[(size_t)(lane + 64) * DD + c]);
    if (lane == 0) gv[c] = s;
  } else if (wid < 1280) {
    int c = wid - 1152;
    float s = wave_sum(wkb[lane] * gw[(size_t)lane * DD + c] +
                       wkb[lane + 64] * gw[(size_t)(lane + 64) * DD + c]);
    if (lane == 0) gv[DD + c] = s + gb[c];
  } else if (wid < 1288) {
    int t = wid - 1280;
    const float* a = att_l + (t & 3) * 3 * DD;  // a_k
    const float* w = (t < 4) ? wkw : wkb;
    float s = wave_sum(w[lane] * a[lane] + w[lane + 64] * a[lane + 64]);
    if (lane == 0) kk[t] = s;
  }
}

// ---------------------------------------------------------------------------
// node_pre2: skq[n,h] = K[n]*kk1[h]+kk0[h] + h[n,:]·wqv_a[:,h]
//            svb[n,h] = h[n,:]·wqv_a[:,4+h].  One wave per node. h is bf16.
// ---------------------------------------------------------------------------
__global__ __launch_bounds__(256) void node_pre2(
    const unsigned short* __restrict__ h, const float* __restrict__ Kf,
    const float* __restrict__ wqv_a, const float* __restrict__ kk,
    float* __restrict__ skq, float* __restrict__ svb, int N) {
  __shared__ float W[DD][8];
  __shared__ float kkl[8];
  const int tid = threadIdx.x;
  for (int i = tid; i < DD * 8; i += 256) W[i >> 3][i & 7] = wqv_a[i];
  if (tid < 8) kkl[tid] = kk[tid];
  __syncthreads();
  const int wid = tid >> 6, lane = tid & 63;
  const int n = blockIdx.x * 4 + wid;
  if (n >= N) return;
  const float h0 = bf2f(h[(size_t)n * DD + lane]);
  const float h1 = bf2f(h[(size_t)n * DD + lane + 64]);
  float r[8];
#pragma unroll
  for (int o = 0; o < 8; o++) r[o] = wave_sum(h0 * W[lane][o] + h1 * W[lane + 64][o]);
  if (lane == 0) {
    const float kn = Kf[n];
    *reinterpret_cast<float4*>(skq + (size_t)n * 4) =
        make_float4(r[0] + kn * kkl[0] + kkl[4], r[1] + kn * kkl[1] + kkl[5],
                    r[2] + kn * kkl[2] + kkl[6], r[3] + kn * kkl[3] + kkl[7]);
    *reinterpret_cast<float4*>(svb + (size_t)n * 4) = make_float4(r[4], r[5], r[6], r[7]);
  }
}

// ---------------------------------------------------------------------------
// edge_ex: per-edge softmax weights, AoS float4 per edge (all 4 heads).
// ---------------------------------------------------------------------------
__global__ __launch_bounds__(256) void edge_ex(
    const int* __restrict__ esrc, const int* __restrict__ edst,
    const float* __restrict__ skq, const float* __restrict__ svb,
    float4* __restrict__ ext4, int E) {
  const int e = blockIdx.x * 256 + threadIdx.x;
  if (e >= E) return;
  const int s = esrc[e], d = edst[e];
  const float4 sv = *(const float4*)(svb + (size_t)s * 4);
  const float4 kq = *(const float4*)(skq + (size_t)d * 4);
  float sc[4] = {kq.x + sv.x, kq.y + sv.y, kq.z + sv.z, kq.w + sv.w};
  float ex[4];
#pragma unroll
  for (int hh = 0; hh < 4; hh++) {
    float vv = sc[hh] > 0.f ? sc[hh] : NEG_SLOPE * sc[hh];
    ex[hh] = __expf(fminf(vv, 60.f));
  }
  ext4[e] = make_float4(ex[0], ex[1], ex[2], ex[3]);
}

// ---------------------------------------------------------------------------
// attn_gather: agh[n][h*128+c] = (Σ_e ex^h_e · h[src_e][c]) / Σ_e ex^h_e.
// One wave per node; lane owns cols {lane*2, lane*2+1} of h (4B gather/lane).
// h table is 12.8 MB (L2/L3-resident). Unroll x8.
// ---------------------------------------------------------------------------
__global__ __launch_bounds__(256) void attn_gather(
    const int* __restrict__ rowptr, const int* __restrict__ esrc,
    const float4* __restrict__ ext4, const unsigned short* __restrict__ h,
    unsigned short* __restrict__ agh, int N) {
  const int wid = threadIdx.x >> 6;
  const int lane = threadIdx.x & 63;
  const int n = blockIdx.x * 4 + wid;
  if (n >= N) return;
  const int beg = rowptr[n];
  const int end = rowptr[n + 1];
  const int c0 = lane * 2;

  float a0[4] = {}, a1[4] = {};
  float sumw[4] = {};

  for (int base = beg; base < end; base += 64) {
    const int cnt = min(64, end - base);
    int myidx = 0;
    if (lane < cnt) myidx = esrc[base + lane];
    int j = 0;
    for (; j + 8 <= cnt; j += 8) {
      int s[8];
      unsigned int wv[8];
      float4 ee[8];
#pragma unroll
      for (int u = 0; u < 8; u++) s[u] = __shfl(myidx, j + u, 64);
#pragma unroll
      for (int u = 0; u < 8; u++) wv[u] = *(const unsigned int*)(h + (size_t)s[u] * DD + c0);
#pragma unroll
      for (int u = 0; u < 8; u++) ee[u] = ext4[base + j + u];
#pragma unroll
      for (int u = 0; u < 8; u++) {
        const float lo = bf2f((unsigned short)(wv[u] & 0xffffu));
        const float hi = bf2f((unsigned short)(wv[u] >> 16));
        a0[0] += ee[u].x * lo; a1[0] += ee[u].x * hi;
        a0[1] += ee[u].y * lo; a1[1] += ee[u].y * hi;
        a0[2] += ee[u].z * lo; a1[2] += ee[u].z * hi;
        a0[3] += ee[u].w * lo; a1[3] += ee[u].w * hi;
        sumw[0] += ee[u].x; sumw[1] += ee[u].y;
        sumw[2] += ee[u].z; sumw[3] += ee[u].w;
      }
    }
    for (; j < cnt; j++) {
      const int s0 = __shfl(myidx, j, 64);
      const unsigned int w0 = *(const unsigned int*)(h + (size_t)s0 * DD + c0);
      const float4 ee = ext4[base + j];
      const float lo = bf2f((unsigned short)(w0 & 0xffffu));
      const float hi = bf2f((unsigned short)(w0 >> 16));
      a0[0] += ee.x * lo; a1[0] += ee.x * hi;
      a0[1] += ee.y * lo; a1[1] += ee.y * hi;
      a0[2] += ee.z * lo; a1[2] += ee.z * hi;
      a0[3] += ee.w * lo; a1[3] += ee.w * hi;
      sumw[0] += ee.x; sumw[1] += ee.y; sumw[2] += ee.z; sumw[3] += ee.w;
    }
  }
  const bool has = (end > beg);
#pragma unroll
  for (int hh = 0; hh < 4; hh++) {
    const float inv = has ? 1.f / sumw[hh] : 0.f;
    const unsigned int packed =
        (unsigned int)f2bf(a0[hh] * inv) | ((unsigned int)f2bf(a1[hh] * inv) << 16);
    *(unsigned int*)(agh + (size_t)n * QV + hh * DD + c0) = packed;
  }
}

// ---------------------------------------------------------------------------
extern "C" void kernel_launch(void* const* d_in, const int* in_sizes, int n_in,
                              void* d_out, int out_size, void* d_ws, size_t ws_size,
                              hipStream_t stream) {
  const float* x = (const float*)d_in[0];
  const int* edge = (const int*)d_in[1];
  const float* Kf = (const float*)d_in[2];
  const float* W_in = (const float*)d_in[3];
  const float* b_in = (const float*)d_in[4];
  const float* Wk_w = (const float*)d_in[5];
  const float* Wk_b = (const float*)d_in[6];
  const float* Wq = (const float*)d_in[7];
  const float* Wv = (const float*)d_in[8];
  const float* att = (const float*)d_in[9];
  const float* Wo = (const float*)d_in[10];
  const float* b_l = (const float*)d_in[11];
  const float* ln_g = (const float*)d_in[12];
  const float* ln_b = (const float*)d_in[13];
  const float* gate_w = (const float*)d_in[14];
  const float* gate_b = (const float*)d_in[15];
  const float* W_out = (const float*)d_in[16];
  const float* b_out = (const float*)d_in[17];
  float* out = (float*)d_out;

  const int* src = edge;
  const int* dst = edge + EE;

  // ---- workspace carve-up ----
  char* w = (char*)d_ws;
  auto alloc = [&](size_t bytes) {
    char* p = w;
    w += (bytes + 255) & ~(size_t)255;
    return p;
  };
  unsigned short* h = (unsigned short*)alloc((size_t)NN * DD * 2);     // 12.8 MB
  unsigned short* agh = (unsigned short*)alloc((size_t)NN * QV * 2);   // 51.2 MB
  float* skq = (float*)alloc((size_t)NN * HH * 4);
  float* svb = (float*)alloc((size_t)NN * HH * 4);
  float* wqv_a = (float*)alloc(DD * 8 * 4);
  float* kk = (float*)alloc(8 * 4);
  float* gv = (float*)alloc(2 * DD * 4);
  int* deg = (int*)alloc((size_t)NN * 4);
  int* rowptr = (int*)alloc((size_t)(NN + 1) * 4);
  int* cursor = (int*)alloc((size_t)NN * 4);
  int* esrc = (int*)alloc((size_t)EE * 4);
  int* edst = (int*)alloc((size_t)EE * 4);
  float4* ext4 = (float4*)alloc((size_t)EE * 16);
  int* blocksum = (int*)alloc((size_t)64 * 4);
  unsigned short* Wint = (unsigned short*)alloc((size_t)DD * DD * 2);
  unsigned short* Woutt = (unsigned short*)alloc((size_t)64 * DD * 2);
  unsigned short* Wot = (unsigned short*)alloc((size_t)LL * DD * QV * 2);  // [3][128][512]
  unsigned short* WvoT = (unsigned short*)alloc((size_t)DD * QV * 2);      // [128][512]

  dim3 blk(256);
  const int NB = cdiv(NN, 1024);
  const int GY = cdiv(NN, 64);  // 782

  // ---- CSR build ----
  zero_int<<<cdiv(NN, 256), blk, 0, stream>>>(deg, NN);
  histo_kernel<<<cdiv(EE, 256), blk, 0, stream>>>(dst, deg, EE);
  scan_blocks<<<NB, 1024, 0, stream>>>(deg, rowptr, blocksum, NN);
  scan_sums<<<1, 64, 0, stream>>>(blocksum, rowptr, NB, NN);
  scan_apply<<<cdiv(NN, 256), blk, 0, stream>>>(rowptr, cursor, blocksum, NN);
  scatter_kernel<<<cdiv(EE, 256), blk, 0, stream>>>(src, dst, cursor, esrc, edst, EE);

  // ---- weight transposes ----
  transp_all<<<cdiv(16384 + 8192 + 3 * 65536, 256), blk, 0, stream>>>(
      W_in, W_out, Wo, Wint, Woutt, Wot);

  // ---- h = relu(x @ W_in + b_in)  (bf16 out) ----
  gemm64<float, unsigned short, 1, 128><<<dim3(1, GY), blk, 0, stream>>>(
      x, Wint, b_in, h, NN, DD, DD);

  for (int l = 0; l < LL; l++) {
    const float* wkw = Wk_w + (size_t)l * DD;
    const float* wkb = Wk_b + (size_t)l * DD;
    const float* wq = Wq + (size_t)l * DD * QV;
    const float* wv = Wv + (size_t)l * DD * QV;
    const float* att_l = att + (size_t)l * HH * 3 * DD;
    const float* bl = b_l + (size_t)l * DD;
    const float* lng = ln_g + (size_t)l * DD;
    const float* lnb = ln_b + (size_t)l * DD;
    const float* gw = gate_w + (size_t)l * DD * DD;
    const float* gb = gate_b + (size_t)l * DD;

    layer_pre<<<cdiv(1288, 4), blk, 0, stream>>>(wq, wv, att_l, wkw, wkb, gw, gb, wqv_a, kk, gv);

    // WvoT = (blockdiag(Wv_h) @ Wo)^T  (tiny)
    gemm_wvo<<<dim3(1, 8), blk, 0, stream>>>(wv, Wot + (size_t)l * DD * QV, WvoT);

    // per-node score components
    node_pre2<<<cdiv(NN, 4), blk, 0, stream>>>(h, Kf, wqv_a, kk, skq, svb, NN);

    // per-edge softmax weights (AoS float4)
    edge_ex<<<cdiv(EE, 256), blk, 0, stream>>>(esrc, edst, skq, svb, ext4, EE);

    // gather h-rows weighted per head -> agh
    attn_gather<<<cdiv(NN, 4), blk, 0, stream>>>(rowptr, esrc, ext4, h, agh, NN);

    // h = relu(LN(agh @ Wvo + h)*lng+lnb * gate + bl)  -- fused, in place
    gemm_wo_ln<<<dim3(1, GY), blk, 0, stream>>>(
        agh, WvoT, Kf, gv, lng, lnb, bl, h, NN);
  }

  // ---- out = h @ W_out + b_out  (f32) ----
  gemm64<unsigned short, float, 0, 64><<<dim3(1, GY), blk, 0, stream>>>(
      h, Woutt, b_out, out, NN, 64, DD);
}